// Round 5
// baseline (1735.832 us; speedup 1.0000x reference)
//
#include <hip/hip_runtime.h>

#define B_ 256
#define T_ 1024
#define H_ 64

typedef float f32x2 __attribute__((ext_vector_type(2)));
typedef float f32x4 __attribute__((ext_vector_type(4)));

// fast tanh via v_exp_f32 + v_rcp_f32 (validated: absmax 0.0)
__device__ __forceinline__ float fast_tanh(float x) {
    float e = __builtin_amdgcn_exp2f(2.8853900817779268f * x);
    return 1.0f - 2.0f * __builtin_amdgcn_rcpf(1.0f + e);
}

// butterfly add via DPP: 0xB1=xor1, 0x4E=xor2 (quad), 0x141=row_half_mirror
// (cross-quad within 8-lane half-row; all lanes valid; IEEE add commutative
// so all lanes land bitwise-identical sums).
template<int CTRL>
__device__ __forceinline__ float dpp_addf(float v) {
    int vi = __builtin_bit_cast(int, v);
    int sh = __builtin_amdgcn_update_dpp(0, vi, CTRL, 0xF, 0xF, true);
    return v + __builtin_bit_cast(float, sh);
}
// pure DPP move (gather partner lane's value)
template<int CTRL>
__device__ __forceinline__ float dpp_movf(float v) {
    int vi = __builtin_bit_cast(int, v);
    int sh = __builtin_amdgcn_update_dpp(0, vi, CTRL, 0xF, 0xF, true);
    return __builtin_bit_cast(float, sh);
}

// R8-validated: barrier draining LDS only (no vmcnt drain).
__device__ __forceinline__ void block_sync_lds() {
    asm volatile("s_waitcnt lgkmcnt(0)\n\ts_barrier" ::: "memory");
}

__device__ __forceinline__ float hsum4(f32x4 v) { return (v.x + v.y) + (v.z + v.w); }

// ---- R4: shared-trans activation, one gate per quad lane ----
// Preconditions: acc[0..3] are the COMPLETE reduced gate sums, bitwise-
// identical on all lanes of the unit group. Lane with quad-pos km computes
// act(gate km); 3 dpp quad moves deliver f,g,o to the km==0 lane.
__device__ __forceinline__ void gate_acts(const float acc[4], float bias_,
                                          float xterm, int km,
                                          float& act, float& fv, float& gv, float& ov) {
    float acc_lo = (km & 1) ? acc[1] : acc[0];
    float acc_hi = (km & 1) ? acc[3] : acc[2];
    float pre = ((km & 2) ? acc_hi : acc_lo) + bias_ + xterm;
    const bool isg = (km == 2);
    float kk = isg ? 2.8853900817779268f : -1.4426950408889634f;
    float e = __builtin_amdgcn_exp2f(kk * pre);
    float r = __builtin_amdgcn_rcpf(1.0f + e);
    act = isg ? 1.0f - 2.0f * r : r;
    fv = dpp_movf<0xB1>(act);       // km0 <- km1 (f)
    gv = dpp_movf<0x4E>(act);       // km0 <- km2 (g)
    ov = dpp_movf<0x4E>(fv);        // km0 <- km2's fv = km3's act (o)
}

// ---- heavy role building blocks, NCH=4 (R8/R12-validated geometry) ----
// thread = (j, kc in [0,4)): 4 gate rows x 32-float chunk of [x|h];
// chunk kc at kc*36 floats (conflict-free b128).
__device__ __forceinline__ void load_w_heavy(const float* __restrict__ w_ih,
                                             const float* __restrict__ w_hh,
                                             int j, int kc, f32x4 wt[4][8]) {
    #pragma unroll
    for (int r = 0; r < 4; ++r) {
        const int row = r * H_ + j;
        const float* base = (kc < 2) ? (w_ih + row * H_ + kc * 32)
                                     : (w_hh + row * H_ + (kc - 2) * 32);
        #pragma unroll
        for (int q = 0; q < 8; ++q)
            wt[r][q] = *(const f32x4*)(base + 4 * q);
    }
    #pragma unroll
    for (int r = 0; r < 4; ++r)
        #pragma unroll
        for (int q = 0; q < 8; ++q)
            asm volatile("" : "+v"(wt[r][q]));
}

__device__ __forceinline__ void dot4x32(const float* chunk, const f32x4 wt[4][8],
                                        float acc[4]) {
    const f32x4* xv = (const f32x4*)chunk;
    f32x4 a0 = {0,0,0,0}, a1 = {0,0,0,0}, a2 = {0,0,0,0}, a3 = {0,0,0,0};
    #pragma unroll
    for (int q = 0; q < 8; ++q) {
        f32x4 hq = xv[q];
        a0 = __builtin_elementwise_fma(wt[0][q], hq, a0);
        a1 = __builtin_elementwise_fma(wt[1][q], hq, a1);
        a2 = __builtin_elementwise_fma(wt[2][q], hq, a2);
        a3 = __builtin_elementwise_fma(wt[3][q], hq, a3);
    }
    acc[0] = hsum4(a0); acc[1] = hsum4(a1);
    acc[2] = hsum4(a2); acc[3] = hsum4(a3);
}

// ---- R5: oct geometry (NCH=8), 16-float chunks at kc*20 floats ----
// kc*20 mod 32 = {0,20,8,28,16,4,24,12}: the 8 b128 chunks partition all 32
// banks; same-kc lanes (different j) broadcast. Conflict-free.
__device__ __forceinline__ void load_w_oct(const float* __restrict__ w_ih,
                                           const float* __restrict__ w_hh,
                                           int j, int kc, f32x4 wt[4][4]) {
    #pragma unroll
    for (int r = 0; r < 4; ++r) {
        const int row = r * H_ + j;
        const float* base = (kc < 4) ? (w_ih + row * H_ + kc * 16)
                                     : (w_hh + row * H_ + (kc - 4) * 16);
        #pragma unroll
        for (int q = 0; q < 4; ++q)
            wt[r][q] = *(const f32x4*)(base + 4 * q);
    }
    #pragma unroll
    for (int r = 0; r < 4; ++r)
        #pragma unroll
        for (int q = 0; q < 4; ++q)
            asm volatile("" : "+v"(wt[r][q]));
}

__device__ __forceinline__ void dot4x16(const float* chunk, const f32x4 wt[4][4],
                                        float acc[4]) {
    const f32x4* xv = (const f32x4*)chunk;
    f32x4 a0 = {0,0,0,0}, a1 = {0,0,0,0}, a2 = {0,0,0,0}, a3 = {0,0,0,0};
    #pragma unroll
    for (int q = 0; q < 4; ++q) {
        f32x4 hq = xv[q];
        a0 = __builtin_elementwise_fma(wt[0][q], hq, a0);
        a1 = __builtin_elementwise_fma(wt[1][q], hq, a1);
        a2 = __builtin_elementwise_fma(wt[2][q], hq, a2);
        a3 = __builtin_elementwise_fma(wt[3][q], hq, a3);
    }
    acc[0] = hsum4(a0); acc[1] = hsum4(a1);
    acc[2] = hsum4(a2); acc[3] = hsum4(a3);
}

// ---------------------------------------------------------------------------
// K1': diagonal TRIPLE [L0+L1+L2] (unchanged R4 winner, 911 us).
// ---------------------------------------------------------------------------
__global__ __launch_bounds__(768, 3)
void lstm_tri012(const float* __restrict__ x,      // [B,T]
                 float* __restrict__ hout,         // [B,T,64] = h_L2
                 const float* __restrict__ w_ih0,  // [256]
                 const float* __restrict__ whh0,
                 const float* __restrict__ bih0, const float* __restrict__ bhh0,
                 const float* __restrict__ wih1, const float* __restrict__ whh1,
                 const float* __restrict__ bih1, const float* __restrict__ bhh1,
                 const float* __restrict__ wih2, const float* __restrict__ whh2,
                 const float* __restrict__ bih2, const float* __restrict__ bhh2)
{
    const int b    = blockIdx.x;
    const int tid  = threadIdx.x;
    const int role = tid >> 8;      // 0=L0, 1=L1, 2=L2 (wave-uniform)
    const int loc  = tid & 255;
    const int kc   = loc & 3;
    const int j    = loc >> 2;      // hidden unit

    __shared__ __align__(16) float bufL0[2][80];    // L0 h: 4 chunks x 20
    __shared__ __align__(16) float bufL1[2][144];   // [x|h]: 4 chunks x 36
    __shared__ __align__(16) float bufL2[2][144];

    f32x4 wt[4][8];                 // L0 uses [4][4] portion
    float bias_ = 0.f;              // per-lane: bias of gate kc, unit j
    float w0_   = 0.f;              // L0 only: x-weight of gate kc, unit j

    if (role == 0) {
        #pragma unroll
        for (int r = 0; r < 4; ++r) {
            const int row = r * H_ + j;
            const float* base = whh0 + row * H_ + kc * 16;
            #pragma unroll
            for (int q = 0; q < 4; ++q)
                wt[r][q] = *(const f32x4*)(base + 4 * q);
        }
        #pragma unroll
        for (int r = 0; r < 4; ++r)
            #pragma unroll
            for (int q = 0; q < 4; ++q)
                asm volatile("" : "+v"(wt[r][q]));
        bias_ = bih0[kc*H_+j] + bhh0[kc*H_+j];
        w0_   = w_ih0[kc*H_+j];
    } else {
        const float* wih = (role == 1) ? wih1 : wih2;
        const float* whh = (role == 1) ? whh1 : whh2;
        const float* bih = (role == 1) ? bih1 : bih2;
        const float* bhh = (role == 1) ? bhh1 : bhh2;
        load_w_heavy(wih, whh, j, kc, wt);
        bias_ = bih[kc*H_+j] + bhh[kc*H_+j];
    }
    float c_st = 0.f;
    float xt = (role == 0) ? x[(long)b * T_] : 0.f;

    float (*myBuf)[144] = (role == 1) ? bufL1 : bufL2;

    // LDS init: L0 reads parity 0 at s=0; L1 parity 1 at s=1; L2 parity 0 at s=2.
    if (loc < H_) {
        const int u = loc;
        if (role == 0)      bufL0[0][(u >> 4) * 20 + (u & 15)] = 0.f;         // h_L0[-1]
        else if (role == 1) bufL1[1][(2 + (u >> 5)) * 36 + (u & 31)] = 0.f;   // h_L1[-1]
        else                bufL2[0][(2 + (u >> 5)) * 36 + (u & 31)] = 0.f;   // h_L2[-1]
    }
    block_sync_lds();

    #pragma unroll 2
    for (int s = 0; s <= T_ + 1; ++s) {
        const int rb = s & 1, wb = rb ^ 1;
        const bool active = (role == 0) ? (s < T_)
                          : (role == 1) ? (s >= 1 && s <= T_)
                                        : (s >= 2);
        if (active) {
            if (role == 0) {
                float xn = 0.f;
                if (s + 1 < T_) xn = x[(long)b * T_ + s + 1];   // wave-uniform
                const f32x4* xv = (const f32x4*)&bufL0[rb][kc * 20];
                f32x4 h0 = xv[0], h1 = xv[1], h2 = xv[2], h3 = xv[3];
                f32x4 a0 = {0,0,0,0}, a1 = {0,0,0,0}, a2 = {0,0,0,0}, a3 = {0,0,0,0};
                a0 = __builtin_elementwise_fma(wt[0][0], h0, a0);
                a1 = __builtin_elementwise_fma(wt[1][0], h0, a1);
                a2 = __builtin_elementwise_fma(wt[2][0], h0, a2);
                a3 = __builtin_elementwise_fma(wt[3][0], h0, a3);
                a0 = __builtin_elementwise_fma(wt[0][1], h1, a0);
                a1 = __builtin_elementwise_fma(wt[1][1], h1, a1);
                a2 = __builtin_elementwise_fma(wt[2][1], h1, a2);
                a3 = __builtin_elementwise_fma(wt[3][1], h1, a3);
                a0 = __builtin_elementwise_fma(wt[0][2], h2, a0);
                a1 = __builtin_elementwise_fma(wt[1][2], h2, a1);
                a2 = __builtin_elementwise_fma(wt[2][2], h2, a2);
                a3 = __builtin_elementwise_fma(wt[3][2], h2, a3);
                a0 = __builtin_elementwise_fma(wt[0][3], h3, a0);
                a1 = __builtin_elementwise_fma(wt[1][3], h3, a1);
                a2 = __builtin_elementwise_fma(wt[2][3], h3, a2);
                a3 = __builtin_elementwise_fma(wt[3][3], h3, a3);
                float acc[4];
                acc[0] = hsum4(a0); acc[1] = hsum4(a1);
                acc[2] = hsum4(a2); acc[3] = hsum4(a3);
                acc[0] = dpp_addf<0xB1>(acc[0]); acc[1] = dpp_addf<0xB1>(acc[1]);
                acc[2] = dpp_addf<0xB1>(acc[2]); acc[3] = dpp_addf<0xB1>(acc[3]);
                acc[0] = dpp_addf<0x4E>(acc[0]); acc[1] = dpp_addf<0x4E>(acc[1]);
                acc[2] = dpp_addf<0x4E>(acc[2]); acc[3] = dpp_addf<0x4E>(acc[3]);
                float act, fv, gv, ov;
                gate_acts(acc, bias_, w0_ * xt, kc, act, fv, gv, ov);
                if (kc == 0) {
                    c_st = fv * c_st + act * gv;
                    float h = ov * fast_tanh(c_st);
                    bufL0[wb][(j >> 4) * 20 + (j & 15)] = h;            // own h
                    bufL1[wb][(j >> 5) * 36 + (j & 31)] = h;            // L1's x
                }
                xt = xn;
            } else {
                float acc[4];
                dot4x32(&myBuf[rb][kc * 36], wt, acc);
                acc[0] = dpp_addf<0xB1>(acc[0]); acc[1] = dpp_addf<0xB1>(acc[1]);
                acc[2] = dpp_addf<0xB1>(acc[2]); acc[3] = dpp_addf<0xB1>(acc[3]);
                acc[0] = dpp_addf<0x4E>(acc[0]); acc[1] = dpp_addf<0x4E>(acc[1]);
                acc[2] = dpp_addf<0x4E>(acc[2]); acc[3] = dpp_addf<0x4E>(acc[3]);
                float act, fv, gv, ov;
                gate_acts(acc, bias_, 0.f, kc, act, fv, gv, ov);
                if (kc == 0) {
                    c_st = fv * c_st + act * gv;
                    float h = ov * fast_tanh(c_st);
                    myBuf[wb][(2 + (j >> 5)) * 36 + (j & 31)] = h;      // own h
                    if (role == 1)
                        bufL2[wb][(j >> 5) * 36 + (j & 31)] = h;        // L2's x
                    else
                        hout[((long)b * T_ + (s - 2)) * H_ + j] = h;
                }
            }
        }
        block_sync_lds();
    }
}

// ---------------------------------------------------------------------------
// K2'': diagonal PAIR [L3+L4] in OCT geometry (R5). 1024 threads, 16 waves
// (4/SIMD, was 2/SIMD): 8 lanes per unit, 16-float chunks at kc*20, 3-stage
// DPP reduce (xor1, xor2, half-row mirror). Halved per-wave FMA block +
// doubled occupancy to hide the dependency-chain latency that left the
// NCH=4 version at 39% VALUBusy. L3 t=s (x = h_L2 from global, prefetched),
// L4 t=s-1 (x = h_L3 via LDS). In-place on buf: 2-round gap preserved.
// ---------------------------------------------------------------------------
__global__ __launch_bounds__(1024, 4)
void lstm_pair34(const float* __restrict__ xin,   // [B,T,64] h_L2 (aliases hout)
                 float* __restrict__ hout,        // [B,T,64] h_L4
                 const float* __restrict__ wih3, const float* __restrict__ whh3,
                 const float* __restrict__ bih3, const float* __restrict__ bhh3,
                 const float* __restrict__ wih4, const float* __restrict__ whh4,
                 const float* __restrict__ bih4, const float* __restrict__ bhh4)
{
    const int b    = blockIdx.x;
    const int tid  = threadIdx.x;
    const int role = tid >> 9;      // 0=L3 (waves 0-7), 1=L4 (waves 8-15)
    const int loc  = tid & 511;
    const int kc   = loc & 7;       // chunk / lane-in-group
    const int km   = kc & 3;        // gate slot within quad
    const int j    = loc >> 3;      // hidden unit

    __shared__ __align__(16) float bufL3[2][160];   // [x|h]: 8 chunks x 20
    __shared__ __align__(16) float bufL4[2][160];

    const float* wih = (role == 0) ? wih3 : wih4;
    const float* whh = (role == 0) ? whh3 : whh4;
    const float* bih = (role == 0) ? bih3 : bih4;
    const float* bhh = (role == 0) ? bhh3 : bhh4;
    float (*myBuf)[160] = (role == 0) ? bufL3 : bufL4;

    f32x4 wt[4][4];
    load_w_oct(wih, whh, j, kc, wt);

    float bias_ = bih[km*H_+j] + bhh[km*H_+j];
    float c_st = 0.f;

    // LDS init: L3 reads parity 0 at s=0 (x row 0 + h=0); L4 parity 1 at s=1.
    if (tid < H_) {
        const int u = tid;
        bufL3[0][(u >> 4) * 20 + (u & 15)] = xin[(long)b * T_ * H_ + u];
        bufL3[0][(4 + (u >> 4)) * 20 + (u & 15)] = 0.f;
    } else if (tid < 128) {
        const int u = tid - 64;
        bufL4[1][(4 + (u >> 4)) * 20 + (u & 15)] = 0.f;
    }
    block_sync_lds();

    #pragma unroll 2
    for (int s = 0; s <= T_; ++s) {
        const int rb = s & 1, wb = rb ^ 1;
        const bool active = (role == 0) ? (s < T_) : (s >= 1);
        if (active) {
            // L3: prefetch next x row (kc==1 lanes, one float each)
            float xn = 0.f;
            if (role == 0 && kc == 1 && s + 1 < T_)
                xn = xin[((long)b * T_ + s + 1) * H_ + j];

            float acc[4];
            dot4x16(&myBuf[rb][kc * 20], wt, acc);
            acc[0] = dpp_addf<0xB1>(acc[0]);  acc[1] = dpp_addf<0xB1>(acc[1]);
            acc[2] = dpp_addf<0xB1>(acc[2]);  acc[3] = dpp_addf<0xB1>(acc[3]);
            acc[0] = dpp_addf<0x4E>(acc[0]);  acc[1] = dpp_addf<0x4E>(acc[1]);
            acc[2] = dpp_addf<0x4E>(acc[2]);  acc[3] = dpp_addf<0x4E>(acc[3]);
            acc[0] = dpp_addf<0x141>(acc[0]); acc[1] = dpp_addf<0x141>(acc[1]);
            acc[2] = dpp_addf<0x141>(acc[2]); acc[3] = dpp_addf<0x141>(acc[3]);

            float act, fv, gv, ov;
            gate_acts(acc, bias_, 0.f, km, act, fv, gv, ov);
            if (kc == 0) {
                c_st = fv * c_st + act * gv;
                float h = ov * fast_tanh(c_st);
                myBuf[wb][(4 + (j >> 4)) * 20 + (j & 15)] = h;          // own h
                if (role == 0)
                    bufL4[wb][(j >> 4) * 20 + (j & 15)] = h;            // L4's x
                else
                    hout[((long)b * T_ + (s - 1)) * H_ + j] = h;
            }
            if (role == 0 && kc == 1)
                bufL3[wb][(j >> 4) * 20 + (j & 15)] = xn;               // next x row
        }
        block_sync_lds();
    }
}

// MLP head (R3-R15-validated): wave-uniform W1 -> scalar loads. ~25 us.
__global__ __launch_bounds__(256)
void mlp_head_v2(const float* __restrict__ hbuf,
                 const float* __restrict__ W1,
                 const float* __restrict__ b1,
                 const float* __restrict__ W2,
                 const float* __restrict__ b2,
                 float* __restrict__ out)
{
    const long r = (long)blockIdx.x * 256 + threadIdx.x;

    float row[H_];
    const float4* src = (const float4*)(hbuf + r * H_);
    #pragma unroll
    for (int q = 0; q < 16; ++q) {
        float4 v = src[q];
        row[4*q+0] = fmaxf(v.x, 0.f); row[4*q+1] = fmaxf(v.y, 0.f);
        row[4*q+2] = fmaxf(v.z, 0.f); row[4*q+3] = fmaxf(v.w, 0.f);
    }
    #pragma unroll
    for (int q = 0; q < 16; ++q)
        asm volatile("" : "+v"(row[4*q]), "+v"(row[4*q+1]),
                         "+v"(row[4*q+2]), "+v"(row[4*q+3]));

    float acc = b2[0];
    for (int jj = 0; jj < H_; ++jj) {
        const float* wrow = W1 + jj * H_;
        float s0 = 0.f, s1 = 0.f, s2 = 0.f, s3 = 0.f;
        #pragma unroll
        for (int q = 0; q < 16; ++q) {
            s0 += row[4*q+0] * wrow[4*q+0];
            s1 += row[4*q+1] * wrow[4*q+1];
            s2 += row[4*q+2] * wrow[4*q+2];
            s3 += row[4*q+3] * wrow[4*q+3];
        }
        float y = fmaxf(b1[jj] + (s0 + s1) + (s2 + s3), 0.f);
        acc += y * W2[jj];
    }
    out[r] = acc;
}

extern "C" void kernel_launch(void* const* d_in, const int* in_sizes, int n_in,
                              void* d_out, int out_size, void* d_ws, size_t ws_size,
                              hipStream_t stream) {
    const float* x     = (const float*)d_in[0];   // [B,T,1]
    const float* w_ih0 = (const float*)d_in[1];   // [256]
    const float* w_ihr = (const float*)d_in[2];   // [4,256,64]
    const float* w_hh  = (const float*)d_in[3];   // [5,256,64]
    const float* b_ih  = (const float*)d_in[4];   // [5,256]
    const float* b_hh  = (const float*)d_in[5];   // [5,256]
    const float* W1    = (const float*)d_in[6];   // [64,64]
    const float* b1    = (const float*)d_in[7];   // [64]
    const float* W2    = (const float*)d_in[8];   // [64]
    const float* b2    = (const float*)d_in[9];   // [1]
    // d_in[10] = future (0)

    float* out = (float*)d_out;
    float* buf = (float*)d_ws;                    // [B,T,64] fp32 = 64 MB

    const long LW = 4L * H_ * H_;   // 16384 floats per layer weight block
    const long LB = 4L * H_;        // 256 floats per layer bias block

    // K1': [L0+L1+L2] diagonal triple -> buf = h_L2
    lstm_tri012<<<dim3(B_), dim3(768), 0, stream>>>(
        x, buf,
        w_ih0, w_hh + 0 * LW, b_ih + 0 * LB, b_hh + 0 * LB,
        w_ihr + 0 * LW, w_hh + 1 * LW, b_ih + 1 * LB, b_hh + 1 * LB,
        w_ihr + 1 * LW, w_hh + 2 * LW, b_ih + 2 * LB, b_hh + 2 * LB);

    // K2'': [L3+L4] diagonal pair in oct geometry, in-place on buf -> buf = h_L4
    lstm_pair34<<<dim3(B_), dim3(1024), 0, stream>>>(
        buf, buf,
        w_ihr + 2 * LW, w_hh + 3 * LW, b_ih + 3 * LB, b_hh + 3 * LB,
        w_ihr + 3 * LW, w_hh + 4 * LW, b_ih + 4 * LB, b_hh + 4 * LB);

    mlp_head_v2<<<dim3((B_ * T_) / 256), dim3(256), 0, stream>>>(
        buf, W1, b1, W2, b2, out);
}

// Round 6
// 1565.242 us; speedup vs baseline: 1.1090x; 1.1090x over previous
//
#include <hip/hip_runtime.h>

#define B_ 256
#define T_ 1024
#define H_ 64

typedef float f32x2 __attribute__((ext_vector_type(2)));
typedef float f32x4 __attribute__((ext_vector_type(4)));

// fast tanh via v_exp_f32 + v_rcp_f32 (validated: absmax 0.0)
__device__ __forceinline__ float fast_tanh(float x) {
    float e = __builtin_amdgcn_exp2f(2.8853900817779268f * x);
    return 1.0f - 2.0f * __builtin_amdgcn_rcpf(1.0f + e);
}

// butterfly add via DPP: 0xB1=xor1, 0x4E=xor2 (NCH=4 -> 2 stages, R8-validated)
template<int CTRL>
__device__ __forceinline__ float dpp_addf(float v) {
    int vi = __builtin_bit_cast(int, v);
    int sh = __builtin_amdgcn_update_dpp(0, vi, CTRL, 0xF, 0xF, true);
    return v + __builtin_bit_cast(float, sh);
}
// pure DPP move (gather partner lane's value)
template<int CTRL>
__device__ __forceinline__ float dpp_movf(float v) {
    int vi = __builtin_bit_cast(int, v);
    int sh = __builtin_amdgcn_update_dpp(0, vi, CTRL, 0xF, 0xF, true);
    return __builtin_bit_cast(float, sh);
}

// R8-validated: barrier draining LDS only (no vmcnt drain).
__device__ __forceinline__ void block_sync_lds() {
    asm volatile("s_waitcnt lgkmcnt(0)\n\ts_barrier" ::: "memory");
}

__device__ __forceinline__ float hsum4(f32x4 v) { return (v.x + v.y) + (v.z + v.w); }

// ---- R4: shared-trans activation, one gate per kc lane ----
// Preconditions: acc[0..3] are the COMPLETE butterfly-reduced gate sums,
// bitwise-identical on all 4 kc lanes (IEEE add commutativity). Lane kc
// computes act(gate kc) with the shared exp2+rcp form; 3 dpp moves deliver
// f,g,o to the kc==0 lane.
__device__ __forceinline__ void gate_acts(const float acc[4], float bias_,
                                          float xterm, int kc,
                                          float& act, float& fv, float& gv, float& ov) {
    float acc_lo = (kc & 1) ? acc[1] : acc[0];
    float acc_hi = (kc & 1) ? acc[3] : acc[2];
    float pre = ((kc & 2) ? acc_hi : acc_lo) + bias_ + xterm;
    const bool isg = (kc == 2);
    float kk = isg ? 2.8853900817779268f : -1.4426950408889634f;
    float e = __builtin_amdgcn_exp2f(kk * pre);
    float r = __builtin_amdgcn_rcpf(1.0f + e);
    act = isg ? 1.0f - 2.0f * r : r;
    fv = dpp_movf<0xB1>(act);       // kc0 <- kc1 (f)
    gv = dpp_movf<0x4E>(act);       // kc0 <- kc2 (g)
    ov = dpp_movf<0x4E>(fv);        // kc0 <- kc2's fv = kc3's act (o)
}

// ---- heavy role building blocks (R8/R12-validated geometry) ----
// thread = (j in [0,64), kc in [0,4)): 4 gate rows {r*64+j} x 32-float chunk
// of [x(0..63) | h(64..127)]; chunk kc at kc*36 floats (conflict-free b128).
__device__ __forceinline__ void load_w_heavy(const float* __restrict__ w_ih,
                                             const float* __restrict__ w_hh,
                                             int j, int kc, f32x4 wt[4][8]) {
    #pragma unroll
    for (int r = 0; r < 4; ++r) {
        const int row = r * H_ + j;
        const float* base = (kc < 2) ? (w_ih + row * H_ + kc * 32)
                                     : (w_hh + row * H_ + (kc - 2) * 32);
        #pragma unroll
        for (int q = 0; q < 8; ++q)
            wt[r][q] = *(const f32x4*)(base + 4 * q);
    }
    #pragma unroll
    for (int r = 0; r < 4; ++r)
        #pragma unroll
        for (int q = 0; q < 8; ++q)
            asm volatile("" : "+v"(wt[r][q]));
}

__device__ __forceinline__ void dot4x32(const float* chunk, const f32x4 wt[4][8],
                                        float acc[4]) {
    const f32x4* xv = (const f32x4*)chunk;
    f32x4 a0 = {0,0,0,0}, a1 = {0,0,0,0}, a2 = {0,0,0,0}, a3 = {0,0,0,0};
    #pragma unroll
    for (int q = 0; q < 8; ++q) {
        f32x4 hq = xv[q];
        a0 = __builtin_elementwise_fma(wt[0][q], hq, a0);
        a1 = __builtin_elementwise_fma(wt[1][q], hq, a1);
        a2 = __builtin_elementwise_fma(wt[2][q], hq, a2);
        a3 = __builtin_elementwise_fma(wt[3][q], hq, a3);
    }
    acc[0] = hsum4(a0); acc[1] = hsum4(a1);
    acc[2] = hsum4(a2); acc[3] = hsum4(a3);
}

// ---------------------------------------------------------------------------
// K1': diagonal TRIPLE [L0+L1+L2] (R4 structure, 911 us).
// R6 change: amdgpu_waves_per_eu(3,3) pins occupancy exactly at our 12-wave
// block -> reg budget 512/3 = 170/wave and no allocator incentive to shrink
// arch-VGPR use; weight arrays should leave AGPRs (kills per-use
// v_accvgpr_read copies identified in R5's post-mortem).
// ---------------------------------------------------------------------------
__global__ __attribute__((amdgpu_flat_work_group_size(768, 768),
                          amdgpu_waves_per_eu(3, 3)))
void lstm_tri012(const float* __restrict__ x,      // [B,T]
                 float* __restrict__ hout,         // [B,T,64] = h_L2
                 const float* __restrict__ w_ih0,  // [256]
                 const float* __restrict__ whh0,
                 const float* __restrict__ bih0, const float* __restrict__ bhh0,
                 const float* __restrict__ wih1, const float* __restrict__ whh1,
                 const float* __restrict__ bih1, const float* __restrict__ bhh1,
                 const float* __restrict__ wih2, const float* __restrict__ whh2,
                 const float* __restrict__ bih2, const float* __restrict__ bhh2)
{
    const int b    = blockIdx.x;
    const int tid  = threadIdx.x;
    const int role = tid >> 8;      // 0=L0, 1=L1, 2=L2 (wave-uniform)
    const int loc  = tid & 255;
    const int kc   = loc & 3;
    const int j    = loc >> 2;      // hidden unit

    __shared__ __align__(16) float bufL0[2][80];    // L0 h: 4 chunks x 20
    __shared__ __align__(16) float bufL1[2][144];   // [x|h]: 4 chunks x 36
    __shared__ __align__(16) float bufL2[2][144];

    f32x4 wt[4][8];                 // L0 uses [4][4] portion
    float bias_ = 0.f;              // per-lane: bias of gate kc, unit j
    float w0_   = 0.f;              // L0 only: x-weight of gate kc, unit j

    if (role == 0) {
        #pragma unroll
        for (int r = 0; r < 4; ++r) {
            const int row = r * H_ + j;
            const float* base = whh0 + row * H_ + kc * 16;
            #pragma unroll
            for (int q = 0; q < 4; ++q)
                wt[r][q] = *(const f32x4*)(base + 4 * q);
        }
        #pragma unroll
        for (int r = 0; r < 4; ++r)
            #pragma unroll
            for (int q = 0; q < 4; ++q)
                asm volatile("" : "+v"(wt[r][q]));
        bias_ = bih0[kc*H_+j] + bhh0[kc*H_+j];
        w0_   = w_ih0[kc*H_+j];
    } else {
        const float* wih = (role == 1) ? wih1 : wih2;
        const float* whh = (role == 1) ? whh1 : whh2;
        const float* bih = (role == 1) ? bih1 : bih2;
        const float* bhh = (role == 1) ? bhh1 : bhh2;
        load_w_heavy(wih, whh, j, kc, wt);
        bias_ = bih[kc*H_+j] + bhh[kc*H_+j];
    }
    float c_st = 0.f;
    float xt = (role == 0) ? x[(long)b * T_] : 0.f;

    float (*myBuf)[144] = (role == 1) ? bufL1 : bufL2;

    // LDS init: L0 reads parity 0 at s=0; L1 parity 1 at s=1; L2 parity 0 at s=2.
    if (loc < H_) {
        const int u = loc;
        if (role == 0)      bufL0[0][(u >> 4) * 20 + (u & 15)] = 0.f;         // h_L0[-1]
        else if (role == 1) bufL1[1][(2 + (u >> 5)) * 36 + (u & 31)] = 0.f;   // h_L1[-1]
        else                bufL2[0][(2 + (u >> 5)) * 36 + (u & 31)] = 0.f;   // h_L2[-1]
    }
    block_sync_lds();

    #pragma unroll 2
    for (int s = 0; s <= T_ + 1; ++s) {
        const int rb = s & 1, wb = rb ^ 1;
        const bool active = (role == 0) ? (s < T_)
                          : (role == 1) ? (s >= 1 && s <= T_)
                                        : (s >= 2);
        if (active) {
            if (role == 0) {
                float xn = 0.f;
                if (s + 1 < T_) xn = x[(long)b * T_ + s + 1];   // wave-uniform
                const f32x4* xv = (const f32x4*)&bufL0[rb][kc * 20];
                f32x4 h0 = xv[0], h1 = xv[1], h2 = xv[2], h3 = xv[3];
                f32x4 a0 = {0,0,0,0}, a1 = {0,0,0,0}, a2 = {0,0,0,0}, a3 = {0,0,0,0};
                a0 = __builtin_elementwise_fma(wt[0][0], h0, a0);
                a1 = __builtin_elementwise_fma(wt[1][0], h0, a1);
                a2 = __builtin_elementwise_fma(wt[2][0], h0, a2);
                a3 = __builtin_elementwise_fma(wt[3][0], h0, a3);
                a0 = __builtin_elementwise_fma(wt[0][1], h1, a0);
                a1 = __builtin_elementwise_fma(wt[1][1], h1, a1);
                a2 = __builtin_elementwise_fma(wt[2][1], h1, a2);
                a3 = __builtin_elementwise_fma(wt[3][1], h1, a3);
                a0 = __builtin_elementwise_fma(wt[0][2], h2, a0);
                a1 = __builtin_elementwise_fma(wt[1][2], h2, a1);
                a2 = __builtin_elementwise_fma(wt[2][2], h2, a2);
                a3 = __builtin_elementwise_fma(wt[3][2], h2, a3);
                a0 = __builtin_elementwise_fma(wt[0][3], h3, a0);
                a1 = __builtin_elementwise_fma(wt[1][3], h3, a1);
                a2 = __builtin_elementwise_fma(wt[2][3], h3, a2);
                a3 = __builtin_elementwise_fma(wt[3][3], h3, a3);
                float acc[4];
                acc[0] = hsum4(a0); acc[1] = hsum4(a1);
                acc[2] = hsum4(a2); acc[3] = hsum4(a3);
                acc[0] = dpp_addf<0xB1>(acc[0]); acc[1] = dpp_addf<0xB1>(acc[1]);
                acc[2] = dpp_addf<0xB1>(acc[2]); acc[3] = dpp_addf<0xB1>(acc[3]);
                acc[0] = dpp_addf<0x4E>(acc[0]); acc[1] = dpp_addf<0x4E>(acc[1]);
                acc[2] = dpp_addf<0x4E>(acc[2]); acc[3] = dpp_addf<0x4E>(acc[3]);
                float act, fv, gv, ov;
                gate_acts(acc, bias_, w0_ * xt, kc, act, fv, gv, ov);
                if (kc == 0) {
                    c_st = fv * c_st + act * gv;
                    float h = ov * fast_tanh(c_st);
                    bufL0[wb][(j >> 4) * 20 + (j & 15)] = h;            // own h
                    bufL1[wb][(j >> 5) * 36 + (j & 31)] = h;            // L1's x
                }
                xt = xn;
            } else {
                float acc[4];
                dot4x32(&myBuf[rb][kc * 36], wt, acc);
                acc[0] = dpp_addf<0xB1>(acc[0]); acc[1] = dpp_addf<0xB1>(acc[1]);
                acc[2] = dpp_addf<0xB1>(acc[2]); acc[3] = dpp_addf<0xB1>(acc[3]);
                acc[0] = dpp_addf<0x4E>(acc[0]); acc[1] = dpp_addf<0x4E>(acc[1]);
                acc[2] = dpp_addf<0x4E>(acc[2]); acc[3] = dpp_addf<0x4E>(acc[3]);
                float act, fv, gv, ov;
                gate_acts(acc, bias_, 0.f, kc, act, fv, gv, ov);
                if (kc == 0) {
                    c_st = fv * c_st + act * gv;
                    float h = ov * fast_tanh(c_st);
                    myBuf[wb][(2 + (j >> 5)) * 36 + (j & 31)] = h;      // own h
                    if (role == 1)
                        bufL2[wb][(j >> 5) * 36 + (j & 31)] = h;        // L2's x
                    else
                        hout[((long)b * T_ + (s - 2)) * H_ + j] = h;
                }
            }
        }
        block_sync_lds();
    }
}

// ---------------------------------------------------------------------------
// K2': diagonal PAIR [L3+L4], both heavy roles (reverted to R4 NCH=4, 606 us;
// R5's oct geometry regressed via AGPR-copy tax). L3 t=s (x = h_L2 from
// global, prefetched), L4 t=s-1 (x = h_L3 via LDS). In-place on buf.
// R6 change: amdgpu_waves_per_eu(2,2) -> reg budget 256/wave, weights should
// be pure arch-VGPR (demand ~175), killing the residual AGPR copies.
// ---------------------------------------------------------------------------
__global__ __attribute__((amdgpu_flat_work_group_size(512, 512),
                          amdgpu_waves_per_eu(2, 2)))
void lstm_pair34(const float* __restrict__ xin,   // [B,T,64] h_L2 (aliases hout)
                 float* __restrict__ hout,        // [B,T,64] h_L4
                 const float* __restrict__ wih3, const float* __restrict__ whh3,
                 const float* __restrict__ bih3, const float* __restrict__ bhh3,
                 const float* __restrict__ wih4, const float* __restrict__ whh4,
                 const float* __restrict__ bih4, const float* __restrict__ bhh4)
{
    const int b    = blockIdx.x;
    const int tid  = threadIdx.x;
    const int role = tid >> 8;      // 0=L3, 1=L4 (wave-uniform)
    const int loc  = tid & 255;
    const int kc   = loc & 3;
    const int j    = loc >> 2;

    __shared__ __align__(16) float bufL3[2][144];
    __shared__ __align__(16) float bufL4[2][144];

    const float* wih = (role == 0) ? wih3 : wih4;
    const float* whh = (role == 0) ? whh3 : whh4;
    const float* bih = (role == 0) ? bih3 : bih4;
    const float* bhh = (role == 0) ? bhh3 : bhh4;
    float (*myBuf)[144] = (role == 0) ? bufL3 : bufL4;

    f32x4 wt[4][8];
    load_w_heavy(wih, whh, j, kc, wt);

    float bias_ = bih[kc*H_+j] + bhh[kc*H_+j];
    float c_st = 0.f;

    // LDS init: L3 reads parity 0 at s=0 (x row 0 + h=0); L4 parity 1 at s=1.
    if (tid < H_) {
        const int u = tid;
        bufL3[0][(u >> 5) * 36 + (u & 31)] = xin[(long)b * T_ * H_ + u];
        bufL3[0][(2 + (u >> 5)) * 36 + (u & 31)] = 0.f;
    } else if (tid < 128) {
        const int u = tid - 64;
        bufL4[1][(2 + (u >> 5)) * 36 + (u & 31)] = 0.f;
    }
    block_sync_lds();

    #pragma unroll 2
    for (int s = 0; s <= T_; ++s) {
        const int rb = s & 1, wb = rb ^ 1;
        const bool active = (role == 0) ? (s < T_) : (s >= 1);
        if (active) {
            // L3: prefetch next x row (kc==1 lanes, one float each)
            float xn = 0.f;
            if (role == 0 && kc == 1 && s + 1 < T_)
                xn = xin[((long)b * T_ + s + 1) * H_ + j];

            float acc[4];
            dot4x32(&myBuf[rb][kc * 36], wt, acc);
            acc[0] = dpp_addf<0xB1>(acc[0]); acc[1] = dpp_addf<0xB1>(acc[1]);
            acc[2] = dpp_addf<0xB1>(acc[2]); acc[3] = dpp_addf<0xB1>(acc[3]);
            acc[0] = dpp_addf<0x4E>(acc[0]); acc[1] = dpp_addf<0x4E>(acc[1]);
            acc[2] = dpp_addf<0x4E>(acc[2]); acc[3] = dpp_addf<0x4E>(acc[3]);

            float act, fv, gv, ov;
            gate_acts(acc, bias_, 0.f, kc, act, fv, gv, ov);
            if (kc == 0) {
                c_st = fv * c_st + act * gv;
                float h = ov * fast_tanh(c_st);
                myBuf[wb][(2 + (j >> 5)) * 36 + (j & 31)] = h;          // own h
                if (role == 0)
                    bufL4[wb][(j >> 5) * 36 + (j & 31)] = h;            // L4's x
                else
                    hout[((long)b * T_ + (s - 1)) * H_ + j] = h;
            }
            if (role == 0 && kc == 1)
                bufL3[wb][(j >> 5) * 36 + (j & 31)] = xn;               // next x row
        }
        block_sync_lds();
    }
}

// MLP head (R3-R15-validated): wave-uniform W1 -> scalar loads. ~25 us.
__global__ __launch_bounds__(256)
void mlp_head_v2(const float* __restrict__ hbuf,
                 const float* __restrict__ W1,
                 const float* __restrict__ b1,
                 const float* __restrict__ W2,
                 const float* __restrict__ b2,
                 float* __restrict__ out)
{
    const long r = (long)blockIdx.x * 256 + threadIdx.x;

    float row[H_];
    const float4* src = (const float4*)(hbuf + r * H_);
    #pragma unroll
    for (int q = 0; q < 16; ++q) {
        float4 v = src[q];
        row[4*q+0] = fmaxf(v.x, 0.f); row[4*q+1] = fmaxf(v.y, 0.f);
        row[4*q+2] = fmaxf(v.z, 0.f); row[4*q+3] = fmaxf(v.w, 0.f);
    }
    #pragma unroll
    for (int q = 0; q < 16; ++q)
        asm volatile("" : "+v"(row[4*q]), "+v"(row[4*q+1]),
                         "+v"(row[4*q+2]), "+v"(row[4*q+3]));

    float acc = b2[0];
    for (int jj = 0; jj < H_; ++jj) {
        const float* wrow = W1 + jj * H_;
        float s0 = 0.f, s1 = 0.f, s2 = 0.f, s3 = 0.f;
        #pragma unroll
        for (int q = 0; q < 16; ++q) {
            s0 += row[4*q+0] * wrow[4*q+0];
            s1 += row[4*q+1] * wrow[4*q+1];
            s2 += row[4*q+2] * wrow[4*q+2];
            s3 += row[4*q+3] * wrow[4*q+3];
        }
        float y = fmaxf(b1[jj] + (s0 + s1) + (s2 + s3), 0.f);
        acc += y * W2[jj];
    }
    out[r] = acc;
}

extern "C" void kernel_launch(void* const* d_in, const int* in_sizes, int n_in,
                              void* d_out, int out_size, void* d_ws, size_t ws_size,
                              hipStream_t stream) {
    const float* x     = (const float*)d_in[0];   // [B,T,1]
    const float* w_ih0 = (const float*)d_in[1];   // [256]
    const float* w_ihr = (const float*)d_in[2];   // [4,256,64]
    const float* w_hh  = (const float*)d_in[3];   // [5,256,64]
    const float* b_ih  = (const float*)d_in[4];   // [5,256]
    const float* b_hh  = (const float*)d_in[5];   // [5,256]
    const float* W1    = (const float*)d_in[6];   // [64,64]
    const float* b1    = (const float*)d_in[7];   // [64]
    const float* W2    = (const float*)d_in[8];   // [64]
    const float* b2    = (const float*)d_in[9];   // [1]
    // d_in[10] = future (0)

    float* out = (float*)d_out;
    float* buf = (float*)d_ws;                    // [B,T,64] fp32 = 64 MB

    const long LW = 4L * H_ * H_;   // 16384 floats per layer weight block
    const long LB = 4L * H_;        // 256 floats per layer bias block

    // K1': [L0+L1+L2] diagonal triple -> buf = h_L2
    lstm_tri012<<<dim3(B_), dim3(768), 0, stream>>>(
        x, buf,
        w_ih0, w_hh + 0 * LW, b_ih + 0 * LB, b_hh + 0 * LB,
        w_ihr + 0 * LW, w_hh + 1 * LW, b_ih + 1 * LB, b_hh + 1 * LB,
        w_ihr + 1 * LW, w_hh + 2 * LW, b_ih + 2 * LB, b_hh + 2 * LB);

    // K2': [L3+L4] diagonal pair, in-place on buf -> buf = h_L4
    lstm_pair34<<<dim3(B_), dim3(512), 0, stream>>>(
        buf, buf,
        w_ihr + 2 * LW, w_hh + 3 * LW, b_ih + 3 * LB, b_hh + 3 * LB,
        w_ihr + 3 * LW, w_hh + 4 * LW, b_ih + 4 * LB, b_hh + 4 * LB);

    mlp_head_v2<<<dim3((B_ * T_) / 256), dim3(256), 0, stream>>>(
        buf, W1, b1, W2, b2, out);
}

// Round 7
// 1548.253 us; speedup vs baseline: 1.1212x; 1.0110x over previous
//
#include <hip/hip_runtime.h>

#define B_ 256
#define T_ 1024
#define H_ 64

typedef float f32x2 __attribute__((ext_vector_type(2)));
typedef float f32x4 __attribute__((ext_vector_type(4)));

// fast tanh via v_exp_f32 + v_rcp_f32 (validated: absmax 0.0)
__device__ __forceinline__ float fast_tanh(float x) {
    float e = __builtin_amdgcn_exp2f(2.8853900817779268f * x);
    return 1.0f - 2.0f * __builtin_amdgcn_rcpf(1.0f + e);
}

// butterfly add via DPP: 0xB1=xor1, 0x4E=xor2 (NCH=4 -> 2 stages, R8-validated)
template<int CTRL>
__device__ __forceinline__ float dpp_addf(float v) {
    int vi = __builtin_bit_cast(int, v);
    int sh = __builtin_amdgcn_update_dpp(0, vi, CTRL, 0xF, 0xF, true);
    return v + __builtin_bit_cast(float, sh);
}
// pure DPP move (gather partner lane's value)
template<int CTRL>
__device__ __forceinline__ float dpp_movf(float v) {
    int vi = __builtin_bit_cast(int, v);
    int sh = __builtin_amdgcn_update_dpp(0, vi, CTRL, 0xF, 0xF, true);
    return __builtin_bit_cast(float, sh);
}

// R8-validated: barrier draining LDS only (no vmcnt drain).
__device__ __forceinline__ void block_sync_lds() {
    asm volatile("s_waitcnt lgkmcnt(0)\n\ts_barrier" ::: "memory");
}

__device__ __forceinline__ float hsum4(f32x4 v) { return (v.x + v.y) + (v.z + v.w); }

// ---- R4: shared-trans activation, one gate per kc lane ----
// Preconditions: acc[0..3] are the COMPLETE butterfly-reduced gate sums,
// bitwise-identical on all 4 kc lanes (IEEE add commutativity). Lane kc
// computes act(gate kc) with the shared exp2+rcp form; 3 dpp moves deliver
// f,g,o to the kc==0 lane.
__device__ __forceinline__ void gate_acts(const float acc[4], float bias_,
                                          float xterm, int kc,
                                          float& act, float& fv, float& gv, float& ov) {
    float acc_lo = (kc & 1) ? acc[1] : acc[0];
    float acc_hi = (kc & 1) ? acc[3] : acc[2];
    float pre = ((kc & 2) ? acc_hi : acc_lo) + bias_ + xterm;
    const bool isg = (kc == 2);
    float kk = isg ? 2.8853900817779268f : -1.4426950408889634f;
    float e = __builtin_amdgcn_exp2f(kk * pre);
    float r = __builtin_amdgcn_rcpf(1.0f + e);
    act = isg ? 1.0f - 2.0f * r : r;
    fv = dpp_movf<0xB1>(act);       // kc0 <- kc1 (f)
    gv = dpp_movf<0x4E>(act);       // kc0 <- kc2 (g)
    ov = dpp_movf<0x4E>(fv);        // kc0 <- kc2's fv = kc3's act (o)
}

// ---- heavy role building blocks (R8/R12-validated geometry) ----
// thread = (j in [0,64), kc in [0,4)): 4 gate rows {r*64+j} x 32-float chunk
// of [x(0..63) | h(64..127)]; chunk kc at kc*36 floats (conflict-free b128).
__device__ __forceinline__ void load_w_heavy(const float* __restrict__ w_ih,
                                             const float* __restrict__ w_hh,
                                             int j, int kc, f32x4 wt[4][8]) {
    #pragma unroll
    for (int r = 0; r < 4; ++r) {
        const int row = r * H_ + j;
        const float* base = (kc < 2) ? (w_ih + row * H_ + kc * 32)
                                     : (w_hh + row * H_ + (kc - 2) * 32);
        #pragma unroll
        for (int q = 0; q < 8; ++q)
            wt[r][q] = *(const f32x4*)(base + 4 * q);
    }
    #pragma unroll
    for (int r = 0; r < 4; ++r)
        #pragma unroll
        for (int q = 0; q < 8; ++q)
            asm volatile("" : "+v"(wt[r][q]));
}

__device__ __forceinline__ void dot4x32(const float* chunk, const f32x4 wt[4][8],
                                        float acc[4]) {
    const f32x4* xv = (const f32x4*)chunk;
    f32x4 a0 = {0,0,0,0}, a1 = {0,0,0,0}, a2 = {0,0,0,0}, a3 = {0,0,0,0};
    #pragma unroll
    for (int q = 0; q < 8; ++q) {
        f32x4 hq = xv[q];
        a0 = __builtin_elementwise_fma(wt[0][q], hq, a0);
        a1 = __builtin_elementwise_fma(wt[1][q], hq, a1);
        a2 = __builtin_elementwise_fma(wt[2][q], hq, a2);
        a3 = __builtin_elementwise_fma(wt[3][q], hq, a3);
    }
    acc[0] = hsum4(a0); acc[1] = hsum4(a1);
    acc[2] = hsum4(a2); acc[3] = hsum4(a3);
}

// ---------------------------------------------------------------------------
// K1': diagonal TRIPLE [L0+L1+L2] (R4 winner config, 911 us).
// role 0 = L0 (light: h-only 16-float chunks, scalar-x term), roles 1,2 =
// heavy. L0 t=s, L1 t=s-1, L2 t=s-2. h flows role->role through LDS; L2
// writes global h_L2. Shared-trans gate activations (R4).
// NOTE (R3/R6): launch hints / waves_per_eu do NOT move the 84/86 VGPR/AGPR
// split; launch_bounds(768,3) retained as the measured-best variant.
// ---------------------------------------------------------------------------
__global__ __launch_bounds__(768, 3)
void lstm_tri012(const float* __restrict__ x,      // [B,T]
                 float* __restrict__ hout,         // [B,T,64] = h_L2
                 const float* __restrict__ w_ih0,  // [256]
                 const float* __restrict__ whh0,
                 const float* __restrict__ bih0, const float* __restrict__ bhh0,
                 const float* __restrict__ wih1, const float* __restrict__ whh1,
                 const float* __restrict__ bih1, const float* __restrict__ bhh1,
                 const float* __restrict__ wih2, const float* __restrict__ whh2,
                 const float* __restrict__ bih2, const float* __restrict__ bhh2)
{
    const int b    = blockIdx.x;
    const int tid  = threadIdx.x;
    const int role = tid >> 8;      // 0=L0, 1=L1, 2=L2 (wave-uniform)
    const int loc  = tid & 255;
    const int kc   = loc & 3;
    const int j    = loc >> 2;      // hidden unit

    __shared__ __align__(16) float bufL0[2][80];    // L0 h: 4 chunks x 20
    __shared__ __align__(16) float bufL1[2][144];   // [x|h]: 4 chunks x 36
    __shared__ __align__(16) float bufL2[2][144];

    f32x4 wt[4][8];                 // L0 uses [4][4] portion
    float bias_ = 0.f;              // per-lane: bias of gate kc, unit j
    float w0_   = 0.f;              // L0 only: x-weight of gate kc, unit j

    if (role == 0) {
        #pragma unroll
        for (int r = 0; r < 4; ++r) {
            const int row = r * H_ + j;
            const float* base = whh0 + row * H_ + kc * 16;
            #pragma unroll
            for (int q = 0; q < 4; ++q)
                wt[r][q] = *(const f32x4*)(base + 4 * q);
        }
        #pragma unroll
        for (int r = 0; r < 4; ++r)
            #pragma unroll
            for (int q = 0; q < 4; ++q)
                asm volatile("" : "+v"(wt[r][q]));
        bias_ = bih0[kc*H_+j] + bhh0[kc*H_+j];
        w0_   = w_ih0[kc*H_+j];
    } else {
        const float* wih = (role == 1) ? wih1 : wih2;
        const float* whh = (role == 1) ? whh1 : whh2;
        const float* bih = (role == 1) ? bih1 : bih2;
        const float* bhh = (role == 1) ? bhh1 : bhh2;
        load_w_heavy(wih, whh, j, kc, wt);
        bias_ = bih[kc*H_+j] + bhh[kc*H_+j];
    }
    float c_st = 0.f;
    float xt = (role == 0) ? x[(long)b * T_] : 0.f;

    float (*myBuf)[144] = (role == 1) ? bufL1 : bufL2;

    // LDS init: L0 reads parity 0 at s=0; L1 parity 1 at s=1; L2 parity 0 at s=2.
    if (loc < H_) {
        const int u = loc;
        if (role == 0)      bufL0[0][(u >> 4) * 20 + (u & 15)] = 0.f;         // h_L0[-1]
        else if (role == 1) bufL1[1][(2 + (u >> 5)) * 36 + (u & 31)] = 0.f;   // h_L1[-1]
        else                bufL2[0][(2 + (u >> 5)) * 36 + (u & 31)] = 0.f;   // h_L2[-1]
    }
    block_sync_lds();

    #pragma unroll 2
    for (int s = 0; s <= T_ + 1; ++s) {
        const int rb = s & 1, wb = rb ^ 1;
        const bool active = (role == 0) ? (s < T_)
                          : (role == 1) ? (s >= 1 && s <= T_)
                                        : (s >= 2);
        if (active) {
            if (role == 0) {
                float xn = 0.f;
                if (s + 1 < T_) xn = x[(long)b * T_ + s + 1];   // wave-uniform
                const f32x4* xv = (const f32x4*)&bufL0[rb][kc * 20];
                f32x4 h0 = xv[0], h1 = xv[1], h2 = xv[2], h3 = xv[3];
                f32x4 a0 = {0,0,0,0}, a1 = {0,0,0,0}, a2 = {0,0,0,0}, a3 = {0,0,0,0};
                a0 = __builtin_elementwise_fma(wt[0][0], h0, a0);
                a1 = __builtin_elementwise_fma(wt[1][0], h0, a1);
                a2 = __builtin_elementwise_fma(wt[2][0], h0, a2);
                a3 = __builtin_elementwise_fma(wt[3][0], h0, a3);
                a0 = __builtin_elementwise_fma(wt[0][1], h1, a0);
                a1 = __builtin_elementwise_fma(wt[1][1], h1, a1);
                a2 = __builtin_elementwise_fma(wt[2][1], h1, a2);
                a3 = __builtin_elementwise_fma(wt[3][1], h1, a3);
                a0 = __builtin_elementwise_fma(wt[0][2], h2, a0);
                a1 = __builtin_elementwise_fma(wt[1][2], h2, a1);
                a2 = __builtin_elementwise_fma(wt[2][2], h2, a2);
                a3 = __builtin_elementwise_fma(wt[3][2], h2, a3);
                a0 = __builtin_elementwise_fma(wt[0][3], h3, a0);
                a1 = __builtin_elementwise_fma(wt[1][3], h3, a1);
                a2 = __builtin_elementwise_fma(wt[2][3], h3, a2);
                a3 = __builtin_elementwise_fma(wt[3][3], h3, a3);
                float acc[4];
                acc[0] = hsum4(a0); acc[1] = hsum4(a1);
                acc[2] = hsum4(a2); acc[3] = hsum4(a3);
                acc[0] = dpp_addf<0xB1>(acc[0]); acc[1] = dpp_addf<0xB1>(acc[1]);
                acc[2] = dpp_addf<0xB1>(acc[2]); acc[3] = dpp_addf<0xB1>(acc[3]);
                acc[0] = dpp_addf<0x4E>(acc[0]); acc[1] = dpp_addf<0x4E>(acc[1]);
                acc[2] = dpp_addf<0x4E>(acc[2]); acc[3] = dpp_addf<0x4E>(acc[3]);
                float act, fv, gv, ov;
                gate_acts(acc, bias_, w0_ * xt, kc, act, fv, gv, ov);
                if (kc == 0) {
                    c_st = fv * c_st + act * gv;
                    float h = ov * fast_tanh(c_st);
                    bufL0[wb][(j >> 4) * 20 + (j & 15)] = h;            // own h
                    bufL1[wb][(j >> 5) * 36 + (j & 31)] = h;            // L1's x
                }
                xt = xn;
            } else {
                float acc[4];
                dot4x32(&myBuf[rb][kc * 36], wt, acc);
                acc[0] = dpp_addf<0xB1>(acc[0]); acc[1] = dpp_addf<0xB1>(acc[1]);
                acc[2] = dpp_addf<0xB1>(acc[2]); acc[3] = dpp_addf<0xB1>(acc[3]);
                acc[0] = dpp_addf<0x4E>(acc[0]); acc[1] = dpp_addf<0x4E>(acc[1]);
                acc[2] = dpp_addf<0x4E>(acc[2]); acc[3] = dpp_addf<0x4E>(acc[3]);
                float act, fv, gv, ov;
                gate_acts(acc, bias_, 0.f, kc, act, fv, gv, ov);
                if (kc == 0) {
                    c_st = fv * c_st + act * gv;
                    float h = ov * fast_tanh(c_st);
                    myBuf[wb][(2 + (j >> 5)) * 36 + (j & 31)] = h;      // own h
                    if (role == 1)
                        bufL2[wb][(j >> 5) * 36 + (j & 31)] = h;        // L2's x
                    else
                        hout[((long)b * T_ + (s - 2)) * H_ + j] = h;
                }
            }
        }
        block_sync_lds();
    }
}

// ---------------------------------------------------------------------------
// K2': diagonal PAIR [L3+L4], both heavy roles (R4 winner config, ~606 us).
// L3 t=s (x = h_L2 from global, prefetched), L4 t=s-1 (x = h_L3 via LDS).
// In-place on buf: L3 reads row s+1 at step s, L4 overwrites row s-1 at
// step s -> 2-round gap. Shared-trans gate activations (R4).
// ---------------------------------------------------------------------------
__global__ __launch_bounds__(512, 2)
void lstm_pair34(const float* __restrict__ xin,   // [B,T,64] h_L2 (aliases hout)
                 float* __restrict__ hout,        // [B,T,64] h_L4
                 const float* __restrict__ wih3, const float* __restrict__ whh3,
                 const float* __restrict__ bih3, const float* __restrict__ bhh3,
                 const float* __restrict__ wih4, const float* __restrict__ whh4,
                 const float* __restrict__ bih4, const float* __restrict__ bhh4)
{
    const int b    = blockIdx.x;
    const int tid  = threadIdx.x;
    const int role = tid >> 8;      // 0=L3, 1=L4 (wave-uniform)
    const int loc  = tid & 255;
    const int kc   = loc & 3;
    const int j    = loc >> 2;

    __shared__ __align__(16) float bufL3[2][144];
    __shared__ __align__(16) float bufL4[2][144];

    const float* wih = (role == 0) ? wih3 : wih4;
    const float* whh = (role == 0) ? whh3 : whh4;
    const float* bih = (role == 0) ? bih3 : bih4;
    const float* bhh = (role == 0) ? bhh3 : bhh4;
    float (*myBuf)[144] = (role == 0) ? bufL3 : bufL4;

    f32x4 wt[4][8];
    load_w_heavy(wih, whh, j, kc, wt);

    float bias_ = bih[kc*H_+j] + bhh[kc*H_+j];
    float c_st = 0.f;

    // LDS init: L3 reads parity 0 at s=0 (x row 0 + h=0); L4 parity 1 at s=1.
    if (tid < H_) {
        const int u = tid;
        bufL3[0][(u >> 5) * 36 + (u & 31)] = xin[(long)b * T_ * H_ + u];
        bufL3[0][(2 + (u >> 5)) * 36 + (u & 31)] = 0.f;
    } else if (tid < 128) {
        const int u = tid - 64;
        bufL4[1][(2 + (u >> 5)) * 36 + (u & 31)] = 0.f;
    }
    block_sync_lds();

    #pragma unroll 2
    for (int s = 0; s <= T_; ++s) {
        const int rb = s & 1, wb = rb ^ 1;
        const bool active = (role == 0) ? (s < T_) : (s >= 1);
        if (active) {
            // L3: prefetch next x row (kc==1 lanes, one float each)
            float xn = 0.f;
            if (role == 0 && kc == 1 && s + 1 < T_)
                xn = xin[((long)b * T_ + s + 1) * H_ + j];

            float acc[4];
            dot4x32(&myBuf[rb][kc * 36], wt, acc);
            acc[0] = dpp_addf<0xB1>(acc[0]); acc[1] = dpp_addf<0xB1>(acc[1]);
            acc[2] = dpp_addf<0xB1>(acc[2]); acc[3] = dpp_addf<0xB1>(acc[3]);
            acc[0] = dpp_addf<0x4E>(acc[0]); acc[1] = dpp_addf<0x4E>(acc[1]);
            acc[2] = dpp_addf<0x4E>(acc[2]); acc[3] = dpp_addf<0x4E>(acc[3]);

            float act, fv, gv, ov;
            gate_acts(acc, bias_, 0.f, kc, act, fv, gv, ov);
            if (kc == 0) {
                c_st = fv * c_st + act * gv;
                float h = ov * fast_tanh(c_st);
                myBuf[wb][(2 + (j >> 5)) * 36 + (j & 31)] = h;          // own h
                if (role == 0)
                    bufL4[wb][(j >> 5) * 36 + (j & 31)] = h;            // L4's x
                else
                    hout[((long)b * T_ + (s - 1)) * H_ + j] = h;
            }
            if (role == 0 && kc == 1)
                bufL3[wb][(j >> 5) * 36 + (j & 31)] = xn;               // next x row
        }
        block_sync_lds();
    }
}

// MLP head (R3-R15-validated): wave-uniform W1 -> scalar loads. ~25 us.
__global__ __launch_bounds__(256)
void mlp_head_v2(const float* __restrict__ hbuf,
                 const float* __restrict__ W1,
                 const float* __restrict__ b1,
                 const float* __restrict__ W2,
                 const float* __restrict__ b2,
                 float* __restrict__ out)
{
    const long r = (long)blockIdx.x * 256 + threadIdx.x;

    float row[H_];
    const float4* src = (const float4*)(hbuf + r * H_);
    #pragma unroll
    for (int q = 0; q < 16; ++q) {
        float4 v = src[q];
        row[4*q+0] = fmaxf(v.x, 0.f); row[4*q+1] = fmaxf(v.y, 0.f);
        row[4*q+2] = fmaxf(v.z, 0.f); row[4*q+3] = fmaxf(v.w, 0.f);
    }
    #pragma unroll
    for (int q = 0; q < 16; ++q)
        asm volatile("" : "+v"(row[4*q]), "+v"(row[4*q+1]),
                         "+v"(row[4*q+2]), "+v"(row[4*q+3]));

    float acc = b2[0];
    for (int jj = 0; jj < H_; ++jj) {
        const float* wrow = W1 + jj * H_;
        float s0 = 0.f, s1 = 0.f, s2 = 0.f, s3 = 0.f;
        #pragma unroll
        for (int q = 0; q < 16; ++q) {
            s0 += row[4*q+0] * wrow[4*q+0];
            s1 += row[4*q+1] * wrow[4*q+1];
            s2 += row[4*q+2] * wrow[4*q+2];
            s3 += row[4*q+3] * wrow[4*q+3];
        }
        float y = fmaxf(b1[jj] + (s0 + s1) + (s2 + s3), 0.f);
        acc += y * W2[jj];
    }
    out[r] = acc;
}

extern "C" void kernel_launch(void* const* d_in, const int* in_sizes, int n_in,
                              void* d_out, int out_size, void* d_ws, size_t ws_size,
                              hipStream_t stream) {
    const float* x     = (const float*)d_in[0];   // [B,T,1]
    const float* w_ih0 = (const float*)d_in[1];   // [256]
    const float* w_ihr = (const float*)d_in[2];   // [4,256,64]
    const float* w_hh  = (const float*)d_in[3];   // [5,256,64]
    const float* b_ih  = (const float*)d_in[4];   // [5,256]
    const float* b_hh  = (const float*)d_in[5];   // [5,256]
    const float* W1    = (const float*)d_in[6];   // [64,64]
    const float* b1    = (const float*)d_in[7];   // [64]
    const float* W2    = (const float*)d_in[8];   // [64]
    const float* b2    = (const float*)d_in[9];   // [1]
    // d_in[10] = future (0)

    float* out = (float*)d_out;
    float* buf = (float*)d_ws;                    // [B,T,64] fp32 = 64 MB

    const long LW = 4L * H_ * H_;   // 16384 floats per layer weight block
    const long LB = 4L * H_;        // 256 floats per layer bias block

    // K1': [L0+L1+L2] diagonal triple -> buf = h_L2
    lstm_tri012<<<dim3(B_), dim3(768), 0, stream>>>(
        x, buf,
        w_ih0, w_hh + 0 * LW, b_ih + 0 * LB, b_hh + 0 * LB,
        w_ihr + 0 * LW, w_hh + 1 * LW, b_ih + 1 * LB, b_hh + 1 * LB,
        w_ihr + 1 * LW, w_hh + 2 * LW, b_ih + 2 * LB, b_hh + 2 * LB);

    // K2': [L3+L4] diagonal pair, in-place on buf -> buf = h_L4
    lstm_pair34<<<dim3(B_), dim3(512), 0, stream>>>(
        buf, buf,
        w_ihr + 2 * LW, w_hh + 3 * LW, b_ih + 3 * LB, b_hh + 3 * LB,
        w_ihr + 3 * LW, w_hh + 4 * LW, b_ih + 4 * LB, b_hh + 4 * LB);

    mlp_head_v2<<<dim3((B_ * T_) / 256), dim3(256), 0, stream>>>(
        buf, W1, b1, W2, b2, out);
}